// Round 1
// baseline (4538.273 us; speedup 1.0000x reference)
//
#include <hip/hip_runtime.h>
#include <hip/hip_bf16.h>
#include <hip/hip_fp16.h>

// Problem: B=64, S=512, E=768, H=256 (4H=1024). Bidirectional relu-LSTM + dense(2).
#define B_ 64
#define S_ 512
#define E_ 768
#define H_ 256
#define G_ 1024  // 4H
#define MROWS 32768  // B*S per direction

typedef float f32x4 __attribute__((ext_vector_type(4)));
typedef short short8 __attribute__((ext_vector_type(8)));
typedef _Float16 v2h __attribute__((ext_vector_type(2)));

// ---------------- prep kernels ----------------

// cast x fp32 -> bf16, n divisible by 4
__global__ void cast_x_kernel(const float* __restrict__ x, __hip_bfloat16* __restrict__ xbf, int n) {
    int i = (blockIdx.x * 256 + threadIdx.x) * 4;
    if (i >= n) return;
    float4 v = *(const float4*)(x + i);
    xbf[i + 0] = __float2bfloat16(v.x);
    xbf[i + 1] = __float2bfloat16(v.y);
    xbf[i + 2] = __float2bfloat16(v.z);
    xbf[i + 3] = __float2bfloat16(v.w);
}

// kernel [E][G] fp32 -> kT [dir][G][E] bf16 (transposed for MFMA B-fragments)
__global__ void prep_kT_kernel(const float* __restrict__ kf, const float* __restrict__ kb,
                               __hip_bfloat16* __restrict__ kT) {
    int idx = blockIdx.x * 256 + threadIdx.x;   // over E_*G_
    int dir = blockIdx.y;
    const float* src = dir ? kb : kf;
    int k = idx >> 10;        // E index
    int n = idx & 1023;       // G index
    float v = src[idx];       // coalesced read (n fast)
    kT[(size_t)dir * G_ * E_ + (size_t)n * E_ + k] = __float2bfloat16(v);
}

// rec [256][1024] fp32 -> recP [dir][128][1024] uint (half2 of k-pairs)
__global__ void prep_rec_kernel(const float* __restrict__ rf, const float* __restrict__ rb,
                                unsigned int* __restrict__ recP) {
    int idx = blockIdx.x * 256 + threadIdx.x;   // over 128*1024
    int dir = blockIdx.y;
    const float* src = dir ? rb : rf;
    int k2 = idx >> 10;
    int col = idx & 1023;
    float a = src[(size_t)(2 * k2) * G_ + col];
    float b = src[(size_t)(2 * k2 + 1) * G_ + col];
    v2h p;
    p[0] = (_Float16)a;
    p[1] = (_Float16)b;
    recP[(size_t)dir * 128 * G_ + idx] = __builtin_bit_cast(unsigned int, p);
}

// ---------------- xz GEMM (bf16 MFMA, no LDS; kT is L2-resident) ----------------
// xz[dir][r][g] = x[b, src_s] @ kernel[dir] + bias[dir], r=(b,s), src_s = dir? 511-s : s
__global__ __launch_bounds__(256) void gemm_xz_kernel(
        const __hip_bfloat16* __restrict__ xbf,   // [B*S][E]
        const __hip_bfloat16* __restrict__ kT,    // [2][G][E]
        const float* __restrict__ bias_f, const float* __restrict__ bias_b,
        __hip_bfloat16* __restrict__ xz) {        // [2][MROWS][G]
    int dir  = blockIdx.z;
    int nblk = blockIdx.x;      // 0..15  (G/64)
    int mblk = blockIdx.y;      // 0..511 (MROWS/64)
    int wave = threadIdx.x >> 6;
    int lane = threadIdx.x & 63;
    int m0 = mblk * 64 + wave * 16;       // this wave's 16 rows (dir-local)
    int lm = lane & 15;
    int lk = (lane >> 4) * 8;
    int r = m0 + lm;
    int b = r >> 9, s = r & 511;
    int src_row = (b << 9) | (dir ? (511 - s) : s);
    const __hip_bfloat16* arow = xbf + (size_t)src_row * E_ + lk;
    const __hip_bfloat16* kbase = kT + (size_t)dir * G_ * E_;
    int n0 = nblk * 64;

    f32x4 acc[4];
#pragma unroll
    for (int t = 0; t < 4; ++t) acc[t] = (f32x4){0.f, 0.f, 0.f, 0.f};

#pragma unroll 2
    for (int kc = 0; kc < E_; kc += 32) {
        short8 afrag = *(const short8*)(arow + kc);
#pragma unroll
        for (int t = 0; t < 4; ++t) {
            const __hip_bfloat16* brow = kbase + (size_t)(n0 + t * 16 + lm) * E_ + kc + lk;
            short8 bfrag = *(const short8*)brow;
            acc[t] = __builtin_amdgcn_mfma_f32_16x16x32_bf16(afrag, bfrag, acc[t], 0, 0, 0);
        }
    }

    // C/D layout (HW-verified): col = lane&15, row = (lane>>4)*4 + reg
    const float* bias = dir ? bias_b : bias_f;
#pragma unroll
    for (int t = 0; t < 4; ++t) {
        int col = n0 + t * 16 + (lane & 15);
        float bv = bias[col];
#pragma unroll
        for (int reg = 0; reg < 4; ++reg) {
            int row = m0 + (lane >> 4) * 4 + reg;
            xz[((size_t)dir * MROWS + row) * G_ + col] = __float2bfloat16(acc[t][reg] + bv);
        }
    }
}

// ---------------- recurrent scan ----------------
__device__ inline float dot2f16(unsigned int rbits, v2h h2, float acc) {
#if __has_builtin(__builtin_amdgcn_fdot2)
    return __builtin_amdgcn_fdot2(__builtin_bit_cast(v2h, rbits), h2, acc, false);
#else
    v2h r = __builtin_bit_cast(v2h, rbits);
    return acc + (float)r[0] * (float)h2[0] + (float)r[1] * (float)h2[1];
#endif
}

__device__ inline float sigmoidf(float x) { return 1.f / (1.f + __expf(-x)); }

// one wg per (batch row, direction). thread tid owns h-index tid (gates tid, 256+tid, 512+tid, 768+tid)
__global__ __launch_bounds__(256) void scan_kernel(
        const __hip_bfloat16* __restrict__ xz,    // [2][MROWS][G]
        const unsigned int* __restrict__ recP,    // [2][128][G] half2-packed
        const float* __restrict__ Wd,             // [S*H][2]
        const float* __restrict__ bd,             // [2]
        float* __restrict__ out) {                // [B][2], pre-zeroed
    int b = blockIdx.x, dir = blockIdx.y, tid = threadIdx.x;
    __shared__ __align__(16) _Float16 sh_h[H_];

    sh_h[tid] = (_Float16)0.f;
    float c = 0.f, pl0 = 0.f, pl1 = 0.f;
    const unsigned int* rp = recP + (size_t)dir * 128 * G_ + tid;
    const __hip_bfloat16* xzb = xz + ((size_t)dir * MROWS + (size_t)b * S_) * G_;
    __syncthreads();

    for (int s = 0; s < S_; ++s) {
        const __hip_bfloat16* xt = xzb + (size_t)s * G_;
        float zi = __bfloat162float(xt[tid]);
        float zf = __bfloat162float(xt[H_ + tid]);
        float zc = __bfloat162float(xt[2 * H_ + tid]);
        float zo = __bfloat162float(xt[3 * H_ + tid]);

        const v2h* hp = (const v2h*)sh_h;
        const unsigned int* r = rp;
#pragma unroll 4
        for (int k2 = 0; k2 < 128; ++k2) {
            v2h h2 = hp[k2];
            zi = dot2f16(r[0],       h2, zi);
            zf = dot2f16(r[H_],      h2, zf);
            zc = dot2f16(r[2 * H_],  h2, zc);
            zo = dot2f16(r[3 * H_],  h2, zo);
            r += G_;
        }

        float ig = sigmoidf(zi);
        float fg = sigmoidf(zf);
        float og = sigmoidf(zo);
        float cc = fmaxf(zc, 0.f);
        c = fg * c + ig * cc;
        float h = og * fmaxf(c, 0.f);

        __syncthreads();              // all reads of old sh_h done
        sh_h[tid] = (_Float16)h;
        __syncthreads();              // h visible for next step

        int t = dir ? (S_ - 1 - s) : s;
        float2 w = ((const float2*)Wd)[t * H_ + tid];
        pl0 = fmaf(h, w.x, pl0);
        pl1 = fmaf(h, w.y, pl1);
    }

    // block reduction of (pl0, pl1)
#pragma unroll
    for (int off = 32; off > 0; off >>= 1) {
        pl0 += __shfl_down(pl0, off);
        pl1 += __shfl_down(pl1, off);
    }
    __shared__ float rbuf[8];
    int w = tid >> 6;
    if ((tid & 63) == 0) { rbuf[w] = pl0; rbuf[4 + w] = pl1; }
    __syncthreads();
    if (tid == 0) {
        float t0 = rbuf[0] + rbuf[1] + rbuf[2] + rbuf[3];
        float t1 = rbuf[4] + rbuf[5] + rbuf[6] + rbuf[7];
        atomicAdd(&out[b * 2 + 0], t0);
        atomicAdd(&out[b * 2 + 1], t1);
    }
    if (dir == 0 && tid < 2) atomicAdd(&out[b * 2 + tid], bd[tid]);
}

// ---------------- launch ----------------
extern "C" void kernel_launch(void* const* d_in, const int* in_sizes, int n_in,
                              void* d_out, int out_size, void* d_ws, size_t ws_size,
                              hipStream_t stream) {
    const float* x        = (const float*)d_in[0];
    const float* kernel_f = (const float*)d_in[1];
    const float* rec_f    = (const float*)d_in[2];
    const float* bias_f   = (const float*)d_in[3];
    const float* kernel_b = (const float*)d_in[4];
    const float* rec_b    = (const float*)d_in[5];
    const float* bias_b   = (const float*)d_in[6];
    const float* Wd       = (const float*)d_in[7];
    const float* bd       = (const float*)d_in[8];
    float* out = (float*)d_out;

    // workspace layout
    char* w = (char*)d_ws;
    __hip_bfloat16* xz  = (__hip_bfloat16*)w;                       // 2*32768*1024*2 = 134217728
    __hip_bfloat16* xbf = (__hip_bfloat16*)(w + 134217728);         // 64*512*768*2   = 50331648
    __hip_bfloat16* kT  = (__hip_bfloat16*)(w + 184549376);         // 2*1024*768*2   = 3145728
    unsigned int*  recP = (unsigned int*) (w + 187695104);          // 2*128*1024*4   = 1048576

    // prep
    int nx = B_ * S_ * E_;
    cast_x_kernel<<<nx / (256 * 4), 256, 0, stream>>>(x, xbf, nx);
    prep_kT_kernel<<<dim3((E_ * G_) / 256, 2), 256, 0, stream>>>(kernel_f, kernel_b, kT);
    prep_rec_kernel<<<dim3((128 * G_) / 256, 2), 256, 0, stream>>>(rec_f, rec_b, recP);

    // xz GEMM: grid (N/64, M/64, dirs)
    gemm_xz_kernel<<<dim3(G_ / 64, MROWS / 64, 2), 256, 0, stream>>>(xbf, kT, bias_f, bias_b, xz);

    // zero logits, then scan accumulates
    hipMemsetAsync(d_out, 0, (size_t)out_size * sizeof(float), stream);
    scan_kernel<<<dim3(B_, 2), 256, 0, stream>>>(xz, recP, Wd, bd, out);
}

// Round 2
// 3149.008 us; speedup vs baseline: 1.4412x; 1.4412x over previous
//
#include <hip/hip_runtime.h>
#include <hip/hip_bf16.h>
#include <hip/hip_fp16.h>

// Problem: B=64, S=512, E=768, H=256 (4H=1024). Bidirectional relu-LSTM + dense(2).
#define B_ 64
#define S_ 512
#define E_ 768
#define H_ 256
#define G_ 1024  // 4H
#define MROWS 32768  // B*S per direction

typedef float f32x4 __attribute__((ext_vector_type(4)));
typedef short short8 __attribute__((ext_vector_type(8)));
typedef _Float16 v2h __attribute__((ext_vector_type(2)));

// ---------------- prep kernels ----------------

// cast x fp32 -> bf16, n divisible by 4
__global__ void cast_x_kernel(const float* __restrict__ x, __hip_bfloat16* __restrict__ xbf, int n) {
    int i = (blockIdx.x * 256 + threadIdx.x) * 4;
    if (i >= n) return;
    float4 v = *(const float4*)(x + i);
    xbf[i + 0] = __float2bfloat16(v.x);
    xbf[i + 1] = __float2bfloat16(v.y);
    xbf[i + 2] = __float2bfloat16(v.z);
    xbf[i + 3] = __float2bfloat16(v.w);
}

// kernel [E][G] fp32 -> kT [dir][G][E] bf16 (transposed for MFMA B-fragments)
__global__ void prep_kT_kernel(const float* __restrict__ kf, const float* __restrict__ kb,
                               __hip_bfloat16* __restrict__ kT) {
    int idx = blockIdx.x * 256 + threadIdx.x;   // over E_*G_
    int dir = blockIdx.y;
    const float* src = dir ? kb : kf;
    int k = idx >> 10;        // E index
    int n = idx & 1023;       // G index
    float v = src[idx];       // coalesced read (n fast)
    kT[(size_t)dir * G_ * E_ + (size_t)n * E_ + k] = __float2bfloat16(v);
}

// rec [256][1024] fp32 -> recQ [dir][32][1024] uint4:
// recQ[d][kk][g] = { h2(rec[8kk+0][g],rec[8kk+1][g]), h2(rec[8kk+2],rec[8kk+3]),
//                    h2(rec[8kk+4],rec[8kk+5]),       h2(rec[8kk+6],rec[8kk+7]) } (col g)
__global__ void prep_recQ_kernel(const float* __restrict__ rf, const float* __restrict__ rb,
                                 unsigned int* __restrict__ recQ) {
    int idx = blockIdx.x * 256 + threadIdx.x;   // over 32*1024*4 = 131072
    int dir = blockIdx.y;
    const float* src = dir ? rb : rf;
    int g  = idx & 1023;
    int u  = (idx >> 10) & 3;
    int kk = idx >> 12;
    int k0 = 8 * kk + 2 * u;
    float a = src[(size_t)k0 * G_ + g];
    float b = src[(size_t)(k0 + 1) * G_ + g];
    v2h p;
    p[0] = (_Float16)a;
    p[1] = (_Float16)b;
    // uint offset = dir*131072 + kk*4096 + g*4 + u  (== uint4 index dir*32768+kk*1024+g, comp u)
    recQ[(size_t)dir * 131072 + (size_t)kk * 4096 + g * 4 + u] = __builtin_bit_cast(unsigned int, p);
}

// ---------------- xz GEMM (bf16 MFMA, no LDS; kT is L2-resident) ----------------
__global__ __launch_bounds__(256) void gemm_xz_kernel(
        const __hip_bfloat16* __restrict__ xbf,   // [B*S][E]
        const __hip_bfloat16* __restrict__ kT,    // [2][G][E]
        const float* __restrict__ bias_f, const float* __restrict__ bias_b,
        __hip_bfloat16* __restrict__ xz) {        // [2][MROWS][G]
    int dir  = blockIdx.z;
    int nblk = blockIdx.x;      // 0..15  (G/64)
    int mblk = blockIdx.y;      // 0..511 (MROWS/64)
    int wave = threadIdx.x >> 6;
    int lane = threadIdx.x & 63;
    int m0 = mblk * 64 + wave * 16;
    int lm = lane & 15;
    int lk = (lane >> 4) * 8;
    int r = m0 + lm;
    int b = r >> 9, s = r & 511;
    int src_row = (b << 9) | (dir ? (511 - s) : s);
    const __hip_bfloat16* arow = xbf + (size_t)src_row * E_ + lk;
    const __hip_bfloat16* kbase = kT + (size_t)dir * G_ * E_;
    int n0 = nblk * 64;

    f32x4 acc[4];
#pragma unroll
    for (int t = 0; t < 4; ++t) acc[t] = (f32x4){0.f, 0.f, 0.f, 0.f};

#pragma unroll 2
    for (int kc = 0; kc < E_; kc += 32) {
        short8 afrag = *(const short8*)(arow + kc);
#pragma unroll
        for (int t = 0; t < 4; ++t) {
            const __hip_bfloat16* brow = kbase + (size_t)(n0 + t * 16 + lm) * E_ + kc + lk;
            short8 bfrag = *(const short8*)brow;
            acc[t] = __builtin_amdgcn_mfma_f32_16x16x32_bf16(afrag, bfrag, acc[t], 0, 0, 0);
        }
    }

    const float* bias = dir ? bias_b : bias_f;
#pragma unroll
    for (int t = 0; t < 4; ++t) {
        int col = n0 + t * 16 + (lane & 15);
        float bv = bias[col];
#pragma unroll
        for (int reg = 0; reg < 4; ++reg) {
            int row = m0 + (lane >> 4) * 4 + reg;
            xz[((size_t)dir * MROWS + row) * G_ + col] = __float2bfloat16(acc[t][reg] + bv);
        }
    }
}

// ---------------- recurrent scan ----------------
__device__ inline float dot2f16(unsigned int rbits, unsigned int hbits, float acc) {
#if __has_builtin(__builtin_amdgcn_fdot2)
    return __builtin_amdgcn_fdot2(__builtin_bit_cast(v2h, rbits),
                                  __builtin_bit_cast(v2h, hbits), acc, false);
#else
    v2h r = __builtin_bit_cast(v2h, rbits);
    v2h h = __builtin_bit_cast(v2h, hbits);
    return acc + (float)r[0] * (float)h[0] + (float)r[1] * (float)h[1];
#endif
}

__device__ inline float sigmoidf(float x) { return 1.f / (1.f + __expf(-x)); }

// one wg (1024 threads) per (batch row, direction). Thread tid owns gate-column tid:
// gate = tid>>8 (keras order [i,f,c,o]), h-index j = tid&255.
__global__ __launch_bounds__(1024) void scan_kernel(
        const __hip_bfloat16* __restrict__ xz,    // [2][MROWS][G]
        const uint4* __restrict__ recQ,           // [2][32][1024] uint4 (k8-packed half2s)
        const float* __restrict__ Wd,             // [S*H][2]
        const float* __restrict__ bd,             // [2]
        float* __restrict__ out) {                // [B][2], pre-zeroed
    int b = blockIdx.x, dir = blockIdx.y, tid = threadIdx.x;
    __shared__ __align__(16) _Float16 sh_h[2][H_];   // double-buffered h (fp16)
    __shared__ float sh_z[G_];                       // z exchange

    if (tid < H_) { sh_h[0][tid] = (_Float16)0.f; }
    float c = 0.f, pl0 = 0.f, pl1 = 0.f;
    const uint4* rq = recQ + (size_t)dir * 32768 + tid;       // advance by 1024 per kk
    const __hip_bfloat16* xzb = xz + ((size_t)dir * MROWS + (size_t)b * S_) * G_ + tid;
    __syncthreads();

    int p = 0;
    for (int s = 0; s < S_; ++s) {
        // independent xz load issued up front; consumed only after the k-loop
        float xzv = __bfloat162float(xzb[(size_t)s * G_]);

        const uint4* hp = (const uint4*)&sh_h[p][0];          // 32 uint4 = 256 halves
        float z = 0.f;
#pragma unroll 8
        for (int kk = 0; kk < 32; ++kk) {
            uint4 r = rq[kk * 1024];                           // 16B coalesced from L2
            uint4 hv = hp[kk];                                 // wave-uniform LDS broadcast
            z = dot2f16(r.x, hv.x, z);
            z = dot2f16(r.y, hv.y, z);
            z = dot2f16(r.z, hv.z, z);
            z = dot2f16(r.w, hv.w, z);
        }
        z += xzv;
        sh_z[tid] = z;
        __syncthreads();                                       // z visible; all h-reads done

        if (tid < H_) {
            float zi = sh_z[tid];
            float zf = sh_z[H_ + tid];
            float zc = sh_z[2 * H_ + tid];
            float zo = sh_z[3 * H_ + tid];
            float ig = sigmoidf(zi);
            float fg = sigmoidf(zf);
            float og = sigmoidf(zo);
            float cc = fmaxf(zc, 0.f);
            c = fg * c + ig * cc;
            float h = og * fmaxf(c, 0.f);
            sh_h[p ^ 1][tid] = (_Float16)h;                    // write NEXT buffer (no race)

            int t = dir ? (S_ - 1 - s) : s;
            float2 w = ((const float2*)Wd)[t * H_ + tid];
            pl0 = fmaf(h, w.x, pl0);
            pl1 = fmaf(h, w.y, pl1);
        }
        __syncthreads();                                       // new h visible
        p ^= 1;
    }

    // reduction over threads 0..255 (4 waves)
    if (tid < H_) {
#pragma unroll
        for (int off = 32; off > 0; off >>= 1) {
            pl0 += __shfl_down(pl0, off);
            pl1 += __shfl_down(pl1, off);
        }
    }
    __shared__ float rbuf[8];
    if (tid < H_ && (tid & 63) == 0) {
        int w = tid >> 6;
        rbuf[w] = pl0; rbuf[4 + w] = pl1;
    }
    __syncthreads();
    if (tid == 0) {
        float t0 = rbuf[0] + rbuf[1] + rbuf[2] + rbuf[3];
        float t1 = rbuf[4] + rbuf[5] + rbuf[6] + rbuf[7];
        atomicAdd(&out[b * 2 + 0], t0);
        atomicAdd(&out[b * 2 + 1], t1);
    }
    if (dir == 0 && tid < 2) atomicAdd(&out[b * 2 + tid], bd[tid]);
}

// ---------------- launch ----------------
extern "C" void kernel_launch(void* const* d_in, const int* in_sizes, int n_in,
                              void* d_out, int out_size, void* d_ws, size_t ws_size,
                              hipStream_t stream) {
    const float* x        = (const float*)d_in[0];
    const float* kernel_f = (const float*)d_in[1];
    const float* rec_f    = (const float*)d_in[2];
    const float* bias_f   = (const float*)d_in[3];
    const float* kernel_b = (const float*)d_in[4];
    const float* rec_b    = (const float*)d_in[5];
    const float* bias_b   = (const float*)d_in[6];
    const float* Wd       = (const float*)d_in[7];
    const float* bd       = (const float*)d_in[8];
    float* out = (float*)d_out;

    // workspace layout
    char* w = (char*)d_ws;
    __hip_bfloat16* xz  = (__hip_bfloat16*)w;                       // 2*32768*1024*2 = 134217728
    __hip_bfloat16* xbf = (__hip_bfloat16*)(w + 134217728);         // 64*512*768*2   = 50331648
    __hip_bfloat16* kT  = (__hip_bfloat16*)(w + 184549376);         // 2*1024*768*2   = 3145728
    unsigned int*  recQ = (unsigned int*) (w + 187695104);          // 2*32*1024*16   = 1048576

    // prep
    int nx = B_ * S_ * E_;
    cast_x_kernel<<<nx / (256 * 4), 256, 0, stream>>>(x, xbf, nx);
    prep_kT_kernel<<<dim3((E_ * G_) / 256, 2), 256, 0, stream>>>(kernel_f, kernel_b, kT);
    prep_recQ_kernel<<<dim3(131072 / 256, 2), 256, 0, stream>>>(rec_f, rec_b, recQ);

    // xz GEMM: grid (N/64, M/64, dirs)
    gemm_xz_kernel<<<dim3(G_ / 64, MROWS / 64, 2), 256, 0, stream>>>(xbf, kT, bias_f, bias_b, xz);

    // zero logits, then scan accumulates
    hipMemsetAsync(d_out, 0, (size_t)out_size * sizeof(float), stream);
    scan_kernel<<<dim3(B_, 2), 1024, 0, stream>>>(xz, (const uint4*)recQ, Wd, bd, out);
}

// Round 3
// 2899.833 us; speedup vs baseline: 1.5650x; 1.0859x over previous
//
#include <hip/hip_runtime.h>
#include <hip/hip_bf16.h>
#include <hip/hip_fp16.h>

// Problem: B=64, S=512, E=768, H=256 (4H=1024). Bidirectional relu-LSTM + dense(2).
#define B_ 64
#define S_ 512
#define E_ 768
#define H_ 256
#define G_ 1024  // 4H
#define MROWS 32768  // B*S per direction

typedef float f32x4 __attribute__((ext_vector_type(4)));
typedef short short8 __attribute__((ext_vector_type(8)));
typedef _Float16 v2h __attribute__((ext_vector_type(2)));

// ---------------- prep kernels ----------------

// cast x fp32 -> bf16, n divisible by 4
__global__ void cast_x_kernel(const float* __restrict__ x, __hip_bfloat16* __restrict__ xbf, int n) {
    int i = (blockIdx.x * 256 + threadIdx.x) * 4;
    if (i >= n) return;
    float4 v = *(const float4*)(x + i);
    xbf[i + 0] = __float2bfloat16(v.x);
    xbf[i + 1] = __float2bfloat16(v.y);
    xbf[i + 2] = __float2bfloat16(v.z);
    xbf[i + 3] = __float2bfloat16(v.w);
}

// kernel [E][G] fp32 -> kT [dir][G][E] bf16 (transposed for MFMA B-fragments)
__global__ void prep_kT_kernel(const float* __restrict__ kf, const float* __restrict__ kb,
                               __hip_bfloat16* __restrict__ kT) {
    int idx = blockIdx.x * 256 + threadIdx.x;   // over E_*G_
    int dir = blockIdx.y;
    const float* src = dir ? kb : kf;
    int k = idx >> 10;        // E index
    int n = idx & 1023;       // G index
    float v = src[idx];       // coalesced read (n fast)
    kT[(size_t)dir * G_ * E_ + (size_t)n * E_ + k] = __float2bfloat16(v);
}

// rec [256][1024] fp32 -> recQ [dir][32][1024] uint4:
// recQ[d][kk][g] = half2 pairs of k = 8kk..8kk+7, column g
__global__ void prep_recQ_kernel(const float* __restrict__ rf, const float* __restrict__ rb,
                                 unsigned int* __restrict__ recQ) {
    int idx = blockIdx.x * 256 + threadIdx.x;   // over 32*1024*4 = 131072
    int dir = blockIdx.y;
    const float* src = dir ? rb : rf;
    int g  = idx & 1023;
    int u  = (idx >> 10) & 3;
    int kk = idx >> 12;
    int k0 = 8 * kk + 2 * u;
    float a = src[(size_t)k0 * G_ + g];
    float b = src[(size_t)(k0 + 1) * G_ + g];
    v2h p;
    p[0] = (_Float16)a;
    p[1] = (_Float16)b;
    recQ[(size_t)dir * 131072 + (size_t)kk * 4096 + g * 4 + u] = __builtin_bit_cast(unsigned int, p);
}

// ---------------- xz GEMM (bf16 MFMA, no LDS; kT is L2-resident) ----------------
__global__ __launch_bounds__(256) void gemm_xz_kernel(
        const __hip_bfloat16* __restrict__ xbf,   // [B*S][E]
        const __hip_bfloat16* __restrict__ kT,    // [2][G][E]
        const float* __restrict__ bias_f, const float* __restrict__ bias_b,
        __hip_bfloat16* __restrict__ xz) {        // [2][MROWS][G]
    int dir  = blockIdx.z;
    int nblk = blockIdx.x;      // 0..15  (G/64)
    int mblk = blockIdx.y;      // 0..511 (MROWS/64)
    int wave = threadIdx.x >> 6;
    int lane = threadIdx.x & 63;
    int m0 = mblk * 64 + wave * 16;
    int lm = lane & 15;
    int lk = (lane >> 4) * 8;
    int r = m0 + lm;
    int b = r >> 9, s = r & 511;
    int src_row = (b << 9) | (dir ? (511 - s) : s);
    const __hip_bfloat16* arow = xbf + (size_t)src_row * E_ + lk;
    const __hip_bfloat16* kbase = kT + (size_t)dir * G_ * E_;
    int n0 = nblk * 64;

    f32x4 acc[4];
#pragma unroll
    for (int t = 0; t < 4; ++t) acc[t] = (f32x4){0.f, 0.f, 0.f, 0.f};

#pragma unroll 2
    for (int kc = 0; kc < E_; kc += 32) {
        short8 afrag = *(const short8*)(arow + kc);
#pragma unroll
        for (int t = 0; t < 4; ++t) {
            const __hip_bfloat16* brow = kbase + (size_t)(n0 + t * 16 + lm) * E_ + kc + lk;
            short8 bfrag = *(const short8*)brow;
            acc[t] = __builtin_amdgcn_mfma_f32_16x16x32_bf16(afrag, bfrag, acc[t], 0, 0, 0);
        }
    }

    const float* bias = dir ? bias_b : bias_f;
#pragma unroll
    for (int t = 0; t < 4; ++t) {
        int col = n0 + t * 16 + (lane & 15);
        float bv = bias[col];
#pragma unroll
        for (int reg = 0; reg < 4; ++reg) {
            int row = m0 + (lane >> 4) * 4 + reg;
            xz[((size_t)dir * MROWS + row) * G_ + col] = __float2bfloat16(acc[t][reg] + bv);
        }
    }
}

// ---------------- recurrent scan (register-resident rec) ----------------
__device__ inline float dot2f16(unsigned int rbits, unsigned int hbits, float acc) {
#if __has_builtin(__builtin_amdgcn_fdot2)
    return __builtin_amdgcn_fdot2(__builtin_bit_cast(v2h, rbits),
                                  __builtin_bit_cast(v2h, hbits), acc, false);
#else
    v2h r = __builtin_bit_cast(v2h, rbits);
    v2h h = __builtin_bit_cast(v2h, hbits);
    return acc + (float)r[0] * (float)h[0] + (float)r[1] * (float)h[1];
#endif
}

__device__ inline float sigmoidf(float x) { return 1.f / (1.f + __expf(-x)); }

// One wg (512 threads = 8 waves, 2/SIMD -> 256 VGPR budget) per (batch, dir).
// Thread t owns columns c0=t (gates i/f) and c1=t+512 (gates c/o).
// rec k=0..191 lives in 192 VGPRs (48 uint4); k=192..255 streams from L2 (128KB/step).
#define KKREG 24   // kk groups of 8 k-values held in registers (24*8 = 192)
__global__ __launch_bounds__(512, 2) void scan_kernel(
        const __hip_bfloat16* __restrict__ xz,    // [2][MROWS][G]
        const uint4* __restrict__ recQ,           // [2][32][1024] uint4
        const float* __restrict__ Wd,             // [S*H][2]
        const float* __restrict__ bd,             // [2]
        float* __restrict__ out) {                // [B][2], pre-zeroed
    int b = blockIdx.x, dir = blockIdx.y, tid = threadIdx.x;
    __shared__ __align__(16) _Float16 sh_h[2][H_];   // double-buffered h (fp16)
    __shared__ float sh_z[G_];                       // z exchange

    const uint4* rqbase = recQ + (size_t)dir * 32768;

    // preload rec k=0..191 for both columns into registers
    uint4 rr0[KKREG], rr1[KKREG];
#pragma unroll
    for (int kk = 0; kk < KKREG; ++kk) {
        rr0[kk] = rqbase[kk * 1024 + tid];
        rr1[kk] = rqbase[kk * 1024 + tid + 512];
    }
    const uint4* sp = rqbase + KKREG * 1024 + tid;    // stream part, advance 1024/uu

    if (tid < H_) { sh_h[0][tid] = (_Float16)0.f; }
    float c = 0.f, pl0 = 0.f, pl1 = 0.f;
    const __hip_bfloat16* xzb = xz + ((size_t)dir * MROWS + (size_t)b * S_) * G_ + tid;
    __syncthreads();

    int p = 0;
    for (int s = 0; s < S_; ++s) {
        // xz for both columns, issued early
        float xz0 = __bfloat162float(xzb[(size_t)s * G_]);
        float xz1 = __bfloat162float(xzb[(size_t)s * G_ + 512]);

        const uint4* hp = (const uint4*)&sh_h[p][0];          // 32 uint4 = 256 halves
        float z0 = 0.f, z1 = 0.f;

        // register part: one h-chunk feeds both columns
#pragma unroll
        for (int kk = 0; kk < KKREG; ++kk) {
            uint4 hv = hp[kk];                                 // wave-uniform LDS broadcast
            uint4 r0 = rr0[kk];
            uint4 r1 = rr1[kk];
            z0 = dot2f16(r0.x, hv.x, z0);
            z0 = dot2f16(r0.y, hv.y, z0);
            z0 = dot2f16(r0.z, hv.z, z0);
            z0 = dot2f16(r0.w, hv.w, z0);
            z1 = dot2f16(r1.x, hv.x, z1);
            z1 = dot2f16(r1.y, hv.y, z1);
            z1 = dot2f16(r1.z, hv.z, z1);
            z1 = dot2f16(r1.w, hv.w, z1);
        }
        // stream part: k=192..255 from L2 (coalesced uint4)
#pragma unroll
        for (int uu = 0; uu < 32 - KKREG; ++uu) {
            uint4 r0 = sp[uu * 1024];
            uint4 r1 = sp[uu * 1024 + 512];
            uint4 hv = hp[KKREG + uu];
            z0 = dot2f16(r0.x, hv.x, z0);
            z0 = dot2f16(r0.y, hv.y, z0);
            z0 = dot2f16(r0.z, hv.z, z0);
            z0 = dot2f16(r0.w, hv.w, z0);
            z1 = dot2f16(r1.x, hv.x, z1);
            z1 = dot2f16(r1.y, hv.y, z1);
            z1 = dot2f16(r1.z, hv.z, z1);
            z1 = dot2f16(r1.w, hv.w, z1);
        }
        sh_z[tid]       = z0 + xz0;
        sh_z[tid + 512] = z1 + xz1;
        __syncthreads();                                       // z visible; h-reads done

        if (tid < H_) {
            float zi = sh_z[tid];
            float zf = sh_z[H_ + tid];
            float zc = sh_z[2 * H_ + tid];
            float zo = sh_z[3 * H_ + tid];
            float ig = sigmoidf(zi);
            float fg = sigmoidf(zf);
            float og = sigmoidf(zo);
            float cc = fmaxf(zc, 0.f);
            c = fg * c + ig * cc;
            float h = og * fmaxf(c, 0.f);
            sh_h[p ^ 1][tid] = (_Float16)h;                    // write NEXT buffer

            int t = dir ? (S_ - 1 - s) : s;
            float2 w = ((const float2*)Wd)[t * H_ + tid];
            pl0 = fmaf(h, w.x, pl0);
            pl1 = fmaf(h, w.y, pl1);
        }
        __syncthreads();                                       // new h visible
        p ^= 1;
    }

    // reduction over threads 0..255 (4 waves)
    if (tid < H_) {
#pragma unroll
        for (int off = 32; off > 0; off >>= 1) {
            pl0 += __shfl_down(pl0, off);
            pl1 += __shfl_down(pl1, off);
        }
    }
    __shared__ float rbuf[8];
    if (tid < H_ && (tid & 63) == 0) {
        int w = tid >> 6;
        rbuf[w] = pl0; rbuf[4 + w] = pl1;
    }
    __syncthreads();
    if (tid == 0) {
        float t0 = rbuf[0] + rbuf[1] + rbuf[2] + rbuf[3];
        float t1 = rbuf[4] + rbuf[5] + rbuf[6] + rbuf[7];
        atomicAdd(&out[b * 2 + 0], t0);
        atomicAdd(&out[b * 2 + 1], t1);
    }
    if (dir == 0 && tid < 2) atomicAdd(&out[b * 2 + tid], bd[tid]);
}

// ---------------- launch ----------------
extern "C" void kernel_launch(void* const* d_in, const int* in_sizes, int n_in,
                              void* d_out, int out_size, void* d_ws, size_t ws_size,
                              hipStream_t stream) {
    const float* x        = (const float*)d_in[0];
    const float* kernel_f = (const float*)d_in[1];
    const float* rec_f    = (const float*)d_in[2];
    const float* bias_f   = (const float*)d_in[3];
    const float* kernel_b = (const float*)d_in[4];
    const float* rec_b    = (const float*)d_in[5];
    const float* bias_b   = (const float*)d_in[6];
    const float* Wd       = (const float*)d_in[7];
    const float* bd       = (const float*)d_in[8];
    float* out = (float*)d_out;

    // workspace layout
    char* w = (char*)d_ws;
    __hip_bfloat16* xz  = (__hip_bfloat16*)w;                       // 2*32768*1024*2 = 134217728
    __hip_bfloat16* xbf = (__hip_bfloat16*)(w + 134217728);         // 64*512*768*2   = 50331648
    __hip_bfloat16* kT  = (__hip_bfloat16*)(w + 184549376);         // 2*1024*768*2   = 3145728
    unsigned int*  recQ = (unsigned int*) (w + 187695104);          // 2*32*1024*16   = 1048576

    // prep
    int nx = B_ * S_ * E_;
    cast_x_kernel<<<nx / (256 * 4), 256, 0, stream>>>(x, xbf, nx);
    prep_kT_kernel<<<dim3((E_ * G_) / 256, 2), 256, 0, stream>>>(kernel_f, kernel_b, kT);
    prep_recQ_kernel<<<dim3(131072 / 256, 2), 256, 0, stream>>>(rec_f, rec_b, recQ);

    // xz GEMM: grid (N/64, M/64, dirs)
    gemm_xz_kernel<<<dim3(G_ / 64, MROWS / 64, 2), 256, 0, stream>>>(xbf, kT, bias_f, bias_b, xz);

    // zero logits, then scan accumulates
    hipMemsetAsync(d_out, 0, (size_t)out_size * sizeof(float), stream);
    scan_kernel<<<dim3(B_, 2), 512, 0, stream>>>(xz, (const uint4*)recQ, Wd, bd, out);
}

// Round 4
// 1866.367 us; speedup vs baseline: 2.4316x; 1.5537x over previous
//
#include <hip/hip_runtime.h>
#include <hip/hip_bf16.h>
#include <hip/hip_fp16.h>

// Problem: B=64, S=512, E=768, H=256 (4H=1024). Bidirectional relu-LSTM + dense(2).
#define B_ 64
#define S_ 512
#define E_ 768
#define H_ 256
#define G_ 1024  // 4H
#define MROWS 32768  // B*S per direction

typedef float f32x4 __attribute__((ext_vector_type(4)));
typedef float f32x16 __attribute__((ext_vector_type(16)));
typedef short short8 __attribute__((ext_vector_type(8)));
typedef _Float16 v2h __attribute__((ext_vector_type(2)));

// ---------------- prep kernels ----------------

// cast x fp32 -> bf16, n divisible by 4
__global__ void cast_x_kernel(const float* __restrict__ x, __hip_bfloat16* __restrict__ xbf, int n) {
    int i = (blockIdx.x * 256 + threadIdx.x) * 4;
    if (i >= n) return;
    float4 v = *(const float4*)(x + i);
    xbf[i + 0] = __float2bfloat16(v.x);
    xbf[i + 1] = __float2bfloat16(v.y);
    xbf[i + 2] = __float2bfloat16(v.z);
    xbf[i + 3] = __float2bfloat16(v.w);
}

// kernel [E][G] fp32 -> kT [dir][G][E] bf16 (transposed for MFMA B-fragments)
__global__ void prep_kT_kernel(const float* __restrict__ kf, const float* __restrict__ kb,
                               __hip_bfloat16* __restrict__ kT) {
    int idx = blockIdx.x * 256 + threadIdx.x;   // over E_*G_
    int dir = blockIdx.y;
    const float* src = dir ? kb : kf;
    int k = idx >> 10;        // E index
    int n = idx & 1023;       // G index
    float v = src[idx];       // coalesced read (n fast)
    kT[(size_t)dir * G_ * E_ + (size_t)n * E_ + k] = __float2bfloat16(v);
}

// rec [256][1024] fp32 -> recQ [dir][32][1024] uint4:
// recQ[d][kk][g] = half2 pairs of k = 8kk..8kk+7, column g
__global__ void prep_recQ_kernel(const float* __restrict__ rf, const float* __restrict__ rb,
                                 unsigned int* __restrict__ recQ) {
    int idx = blockIdx.x * 256 + threadIdx.x;   // over 32*1024*4 = 131072
    int dir = blockIdx.y;
    const float* src = dir ? rb : rf;
    int g  = idx & 1023;
    int u  = (idx >> 10) & 3;
    int kk = idx >> 12;
    int k0 = 8 * kk + 2 * u;
    float a = src[(size_t)k0 * G_ + g];
    float b = src[(size_t)(k0 + 1) * G_ + g];
    v2h p;
    p[0] = (_Float16)a;
    p[1] = (_Float16)b;
    recQ[(size_t)dir * 131072 + (size_t)kk * 4096 + g * 4 + u] = __builtin_bit_cast(unsigned int, p);
}

// ---------------- xz GEMM (bf16 MFMA 32x32x16, no LDS; kT is L2-resident) ----------------
// Per wave: 32 rows x 64 cols (2 accumulator tiles). wg = 4 waves = 128 rows x 64 cols.
__global__ __launch_bounds__(256) void gemm_xz_kernel(
        const __hip_bfloat16* __restrict__ xbf,   // [B*S][E]
        const __hip_bfloat16* __restrict__ kT,    // [2][G][E]
        const float* __restrict__ bias_f, const float* __restrict__ bias_b,
        __hip_bfloat16* __restrict__ xz) {        // [2][MROWS][G]
    int dir  = blockIdx.z;
    int nblk = blockIdx.x;      // 0..15  (G/64)
    int mblk = blockIdx.y;      // 0..255 (MROWS/128)
    int wave = threadIdx.x >> 6;
    int lane = threadIdx.x & 63;
    int m0 = mblk * 128 + wave * 32;
    int lm = lane & 31;                 // A row / B col within tile
    int kq = (lane >> 5) * 8;           // k-offset within 16-chunk
    int r = m0 + lm;
    int b = r >> 9, s = r & 511;
    int src_row = (b << 9) | (dir ? (511 - s) : s);
    const __hip_bfloat16* arow = xbf + (size_t)src_row * E_ + kq;
    const __hip_bfloat16* kbase = kT + (size_t)dir * G_ * E_;
    int n0 = nblk * 64;
    const __hip_bfloat16* brow0 = kbase + (size_t)(n0 + lm) * E_ + kq;
    const __hip_bfloat16* brow1 = kbase + (size_t)(n0 + 32 + lm) * E_ + kq;

    f32x16 acc0 = {}, acc1 = {};

#pragma unroll 4
    for (int kc = 0; kc < E_; kc += 16) {
        short8 afrag = *(const short8*)(arow + kc);
        short8 bf0   = *(const short8*)(brow0 + kc);
        short8 bf1   = *(const short8*)(brow1 + kc);
        acc0 = __builtin_amdgcn_mfma_f32_32x32x16_bf16(afrag, bf0, acc0, 0, 0, 0);
        acc1 = __builtin_amdgcn_mfma_f32_32x32x16_bf16(afrag, bf1, acc1, 0, 0, 0);
    }

    // C/D layout (HW-verified, m74/m101): col = lane&31, row = (reg&3) + 8*(reg>>2) + 4*(lane>>5)
    const float* bias = dir ? bias_b : bias_f;
#pragma unroll
    for (int t = 0; t < 2; ++t) {
        int col = n0 + t * 32 + (lane & 31);
        float bv = bias[col];
        const f32x16& a = t ? acc1 : acc0;
#pragma unroll
        for (int reg = 0; reg < 16; ++reg) {
            int row = m0 + (reg & 3) + 8 * (reg >> 2) + 4 * (lane >> 5);
            xz[((size_t)dir * MROWS + row) * G_ + col] = __float2bfloat16(a[reg] + bv);
        }
    }
}

// ---------------- recurrent scan (reg + LDS + small L2 stream) ----------------
__device__ inline float dot2f16(unsigned int rbits, unsigned int hbits, float acc) {
#if __has_builtin(__builtin_amdgcn_fdot2)
    return __builtin_amdgcn_fdot2(__builtin_bit_cast(v2h, rbits),
                                  __builtin_bit_cast(v2h, hbits), acc, false);
#else
    v2h r = __builtin_bit_cast(v2h, rbits);
    v2h h = __builtin_bit_cast(v2h, hbits);
    return acc + (float)r[0] * (float)h[0] + (float)r[1] * (float)h[1];
#endif
}

__device__ inline float sigmoidf(float x) { return 1.f / (1.f + __expf(-x)); }

// One wg (512 threads = 8 waves) per (batch, dir). NOTE: __launch_bounds__(512) with NO
// second arg — on this toolchain the 2nd arg acts like min-blocks/CU and capped VGPRs at
// 128 last round (spills, WRITE_SIZE 7.7MB). 512 threads alone implies <=256 VGPR cap.
// Thread t owns columns c0=t (gates i/f) and c1=t+512 (gates c/o).
// rec split: kk 0..23 in VGPRs (192), kk 24..26 in LDS (48KB), kk 27..31 streamed from L2.
#define KKREG 24
#define KKLDS 3
__global__ __launch_bounds__(512) void scan_kernel(
        const __hip_bfloat16* __restrict__ xz,    // [2][MROWS][G]
        const uint4* __restrict__ recQ,           // [2][32][1024] uint4
        const float* __restrict__ Wd,             // [S*H][2]
        const float* __restrict__ bd,             // [2]
        float* __restrict__ out) {                // [B][2], pre-zeroed
    int b = blockIdx.x, dir = blockIdx.y, tid = threadIdx.x;
    __shared__ __align__(16) uint4 sh_rec[KKLDS * G_];   // 48 KB
    __shared__ __align__(16) _Float16 sh_h[2][H_];       // 1 KB, double-buffered h
    __shared__ float sh_z[G_];                           // 4 KB z exchange
    __shared__ float rbuf[8];

    const uint4* rqbase = recQ + (size_t)dir * 32768;

    // preload rec kk=0..23 for both columns into registers
    uint4 rr0[KKREG], rr1[KKREG];
#pragma unroll
    for (int kk = 0; kk < KKREG; ++kk) {
        rr0[kk] = rqbase[kk * 1024 + tid];
        rr1[kk] = rqbase[kk * 1024 + tid + 512];
    }
    // stage rec kk=24..26 into LDS (contiguous copy)
#pragma unroll
    for (int j = 0; j < KKLDS * 2; ++j)
        sh_rec[j * 512 + tid] = rqbase[KKREG * 1024 + j * 512 + tid];
    const uint4* sp = rqbase + (KKREG + KKLDS) * 1024 + tid;   // stream part

    if (tid < H_) { sh_h[0][tid] = (_Float16)0.f; }
    float c = 0.f, pl0 = 0.f, pl1 = 0.f;
    const __hip_bfloat16* xzb = xz + ((size_t)dir * MROWS + (size_t)b * S_) * G_ + tid;
    __syncthreads();

    int p = 0;
    for (int s = 0; s < S_; ++s) {
        float xz0 = __bfloat162float(xzb[(size_t)s * G_]);
        float xz1 = __bfloat162float(xzb[(size_t)s * G_ + 512]);

        const uint4* hp = (const uint4*)&sh_h[p][0];          // 32 uint4 = 256 halves
        float z0 = 0.f, z1 = 0.f;

        // register part
#pragma unroll
        for (int kk = 0; kk < KKREG; ++kk) {
            uint4 hv = hp[kk];                                 // wave-uniform broadcast
            uint4 r0 = rr0[kk];
            uint4 r1 = rr1[kk];
            z0 = dot2f16(r0.x, hv.x, z0); z0 = dot2f16(r0.y, hv.y, z0);
            z0 = dot2f16(r0.z, hv.z, z0); z0 = dot2f16(r0.w, hv.w, z0);
            z1 = dot2f16(r1.x, hv.x, z1); z1 = dot2f16(r1.y, hv.y, z1);
            z1 = dot2f16(r1.z, hv.z, z1); z1 = dot2f16(r1.w, hv.w, z1);
        }
        // LDS part (stride-16B ds_read_b128, conflict-free)
#pragma unroll
        for (int j = 0; j < KKLDS; ++j) {
            uint4 hv = hp[KKREG + j];
            uint4 r0 = sh_rec[j * 1024 + tid];
            uint4 r1 = sh_rec[j * 1024 + tid + 512];
            z0 = dot2f16(r0.x, hv.x, z0); z0 = dot2f16(r0.y, hv.y, z0);
            z0 = dot2f16(r0.z, hv.z, z0); z0 = dot2f16(r0.w, hv.w, z0);
            z1 = dot2f16(r1.x, hv.x, z1); z1 = dot2f16(r1.y, hv.y, z1);
            z1 = dot2f16(r1.z, hv.z, z1); z1 = dot2f16(r1.w, hv.w, z1);
        }
        // stream part from L2 (80 KB/step)
#pragma unroll
        for (int u = 0; u < 32 - KKREG - KKLDS; ++u) {
            uint4 r0 = sp[u * 1024];
            uint4 r1 = sp[u * 1024 + 512];
            uint4 hv = hp[KKREG + KKLDS + u];
            z0 = dot2f16(r0.x, hv.x, z0); z0 = dot2f16(r0.y, hv.y, z0);
            z0 = dot2f16(r0.z, hv.z, z0); z0 = dot2f16(r0.w, hv.w, z0);
            z1 = dot2f16(r1.x, hv.x, z1); z1 = dot2f16(r1.y, hv.y, z1);
            z1 = dot2f16(r1.z, hv.z, z1); z1 = dot2f16(r1.w, hv.w, z1);
        }
        sh_z[tid]       = z0 + xz0;
        sh_z[tid + 512] = z1 + xz1;
        __syncthreads();                                       // z visible; h-reads done

        if (tid < H_) {
            float zi = sh_z[tid];
            float zf = sh_z[H_ + tid];
            float zc = sh_z[2 * H_ + tid];
            float zo = sh_z[3 * H_ + tid];
            float ig = sigmoidf(zi);
            float fg = sigmoidf(zf);
            float og = sigmoidf(zo);
            float cc = fmaxf(zc, 0.f);
            c = fg * c + ig * cc;
            float h = og * fmaxf(c, 0.f);
            sh_h[p ^ 1][tid] = (_Float16)h;                    // write NEXT buffer

            int t = dir ? (S_ - 1 - s) : s;
            float2 w = ((const float2*)Wd)[t * H_ + tid];
            pl0 = fmaf(h, w.x, pl0);
            pl1 = fmaf(h, w.y, pl1);
        }
        __syncthreads();                                       // new h visible
        p ^= 1;
    }

    // reduction over threads 0..255 (4 waves)
    if (tid < H_) {
#pragma unroll
        for (int off = 32; off > 0; off >>= 1) {
            pl0 += __shfl_down(pl0, off);
            pl1 += __shfl_down(pl1, off);
        }
    }
    if (tid < H_ && (tid & 63) == 0) {
        int w = tid >> 6;
        rbuf[w] = pl0; rbuf[4 + w] = pl1;
    }
    __syncthreads();
    if (tid == 0) {
        float t0 = rbuf[0] + rbuf[1] + rbuf[2] + rbuf[3];
        float t1 = rbuf[4] + rbuf[5] + rbuf[6] + rbuf[7];
        atomicAdd(&out[b * 2 + 0], t0);
        atomicAdd(&out[b * 2 + 1], t1);
    }
    if (dir == 0 && tid < 2) atomicAdd(&out[b * 2 + tid], bd[tid]);
}

// ---------------- launch ----------------
extern "C" void kernel_launch(void* const* d_in, const int* in_sizes, int n_in,
                              void* d_out, int out_size, void* d_ws, size_t ws_size,
                              hipStream_t stream) {
    const float* x        = (const float*)d_in[0];
    const float* kernel_f = (const float*)d_in[1];
    const float* rec_f    = (const float*)d_in[2];
    const float* bias_f   = (const float*)d_in[3];
    const float* kernel_b = (const float*)d_in[4];
    const float* rec_b    = (const float*)d_in[5];
    const float* bias_b   = (const float*)d_in[6];
    const float* Wd       = (const float*)d_in[7];
    const float* bd       = (const float*)d_in[8];
    float* out = (float*)d_out;

    // workspace layout
    char* w = (char*)d_ws;
    __hip_bfloat16* xz  = (__hip_bfloat16*)w;                       // 2*32768*1024*2 = 134217728
    __hip_bfloat16* xbf = (__hip_bfloat16*)(w + 134217728);         // 64*512*768*2   = 50331648
    __hip_bfloat16* kT  = (__hip_bfloat16*)(w + 184549376);         // 2*1024*768*2   = 3145728
    unsigned int*  recQ = (unsigned int*) (w + 187695104);          // 2*32*1024*16   = 1048576

    // prep
    int nx = B_ * S_ * E_;
    cast_x_kernel<<<nx / (256 * 4), 256, 0, stream>>>(x, xbf, nx);
    prep_kT_kernel<<<dim3((E_ * G_) / 256, 2), 256, 0, stream>>>(kernel_f, kernel_b, kT);
    prep_recQ_kernel<<<dim3(131072 / 256, 2), 256, 0, stream>>>(rec_f, rec_b, recQ);

    // xz GEMM: grid (N/64, M/128, dirs)
    gemm_xz_kernel<<<dim3(G_ / 64, MROWS / 128, 2), 256, 0, stream>>>(xbf, kT, bias_f, bias_b, xz);

    // zero logits, then scan accumulates
    hipMemsetAsync(d_out, 0, (size_t)out_size * sizeof(float), stream);
    scan_kernel<<<dim3(B_, 2), 512, 0, stream>>>(xz, (const uint4*)recQ, Wd, bd, out);
}

// Round 5
// 1500.046 us; speedup vs baseline: 3.0254x; 1.2442x over previous
//
#include <hip/hip_runtime.h>
#include <hip/hip_bf16.h>
#include <hip/hip_fp16.h>

// Problem: B=64, S=512, E=768, H=256 (4H=1024). Bidirectional relu-LSTM + dense(2).
#define B_ 64
#define S_ 512
#define E_ 768
#define H_ 256
#define G_ 1024  // 4H
#define MROWS 32768  // B*S per direction

typedef float f32x4 __attribute__((ext_vector_type(4)));
typedef float f32x16 __attribute__((ext_vector_type(16)));
typedef short short8 __attribute__((ext_vector_type(8)));
typedef _Float16 v2h __attribute__((ext_vector_type(2)));

// ---------------- prep kernels ----------------

// cast x fp32 -> bf16, n divisible by 4
__global__ void cast_x_kernel(const float* __restrict__ x, __hip_bfloat16* __restrict__ xbf, int n) {
    int i = (blockIdx.x * 256 + threadIdx.x) * 4;
    if (i >= n) return;
    float4 v = *(const float4*)(x + i);
    xbf[i + 0] = __float2bfloat16(v.x);
    xbf[i + 1] = __float2bfloat16(v.y);
    xbf[i + 2] = __float2bfloat16(v.z);
    xbf[i + 3] = __float2bfloat16(v.w);
}

// kernel [E][G] fp32 -> kT [dir][G][E] bf16 (transposed for MFMA B-fragments)
__global__ void prep_kT_kernel(const float* __restrict__ kf, const float* __restrict__ kb,
                               __hip_bfloat16* __restrict__ kT) {
    int idx = blockIdx.x * 256 + threadIdx.x;   // over E_*G_
    int dir = blockIdx.y;
    const float* src = dir ? kb : kf;
    int k = idx >> 10;        // E index
    int n = idx & 1023;       // G index
    float v = src[idx];       // coalesced read (n fast)
    kT[(size_t)dir * G_ * E_ + (size_t)n * E_ + k] = __float2bfloat16(v);
}

// rec [256][1024] fp32 -> recQ [dir][32][1024] uint4:
// recQ[d][kk][g] = half2 pairs of k = 8kk..8kk+7, column g
__global__ void prep_recQ_kernel(const float* __restrict__ rf, const float* __restrict__ rb,
                                 unsigned int* __restrict__ recQ) {
    int idx = blockIdx.x * 256 + threadIdx.x;   // over 32*1024*4 = 131072
    int dir = blockIdx.y;
    const float* src = dir ? rb : rf;
    int g  = idx & 1023;
    int u  = (idx >> 10) & 3;
    int kk = idx >> 12;
    int k0 = 8 * kk + 2 * u;
    float a = src[(size_t)k0 * G_ + g];
    float b = src[(size_t)(k0 + 1) * G_ + g];
    v2h p;
    p[0] = (_Float16)a;
    p[1] = (_Float16)b;
    recQ[(size_t)dir * 131072 + (size_t)kk * 4096 + g * 4 + u] = __builtin_bit_cast(unsigned int, p);
}

// ---------------- xz GEMM: LDS-tiled 128x128, BK=32, mfma 32x32x16 ----------------
#define TM 128
#define TN 128
#define BK 32
#define LDA 40   // padded LDS row stride in elements (80 B: 16B-aligned, reduces conflicts)

__global__ __launch_bounds__(256) void gemm_xz_kernel(
        const __hip_bfloat16* __restrict__ xbf,   // [B*S][E]
        const __hip_bfloat16* __restrict__ kT,    // [2][G][E]
        const float* __restrict__ bias_f, const float* __restrict__ bias_b,
        __hip_bfloat16* __restrict__ xz) {        // [2][MROWS][G]
    int dir  = blockIdx.z;
    int nblk = blockIdx.x;      // 0..7   (G/128)
    int mblk = blockIdx.y;      // 0..255 (MROWS/128)
    int tid  = threadIdx.x;
    int wave = tid >> 6, lane = tid & 63;

    __shared__ __hip_bfloat16 shA[TM * LDA];   // 10240 B
    __shared__ __hip_bfloat16 shB[TN * LDA];   // 10240 B

    int m0 = mblk * TM;
    int n0 = nblk * TN;

    // staging: thread t loads 16B chunks c = t and c = t+256 (row = c>>2, k8 = (c&3)*8)
    int rowl0 = tid >> 2;             // 0..63
    int rowl1 = rowl0 + 64;           // 64..127
    int k8    = (tid & 3) * 8;
    // A source rows with dir reversal
    int ar0 = m0 + rowl0, ar1 = m0 + rowl1;
    int sa0 = (ar0 & ~511) | (dir ? (511 - (ar0 & 511)) : (ar0 & 511));
    int sa1 = (ar1 & ~511) | (dir ? (511 - (ar1 & 511)) : (ar1 & 511));
    const __hip_bfloat16* kbase = kT + (size_t)dir * G_ * E_;

    f32x16 acc[4] = {};

    int lm = lane & 31;               // row/col within 32-subtile
    int kq = (lane >> 5) * 8;         // lane's k-offset within a 16-k chunk

    for (int k0 = 0; k0 < E_; k0 += BK) {
        __syncthreads();
        // stage A (two 16B chunks per thread)
        *(short8*)&shA[rowl0 * LDA + k8] = *(const short8*)(xbf + (size_t)sa0 * E_ + k0 + k8);
        *(short8*)&shA[rowl1 * LDA + k8] = *(const short8*)(xbf + (size_t)sa1 * E_ + k0 + k8);
        // stage B
        *(short8*)&shB[rowl0 * LDA + k8] = *(const short8*)(kbase + (size_t)(n0 + rowl0) * E_ + k0 + k8);
        *(short8*)&shB[rowl1 * LDA + k8] = *(const short8*)(kbase + (size_t)(n0 + rowl1) * E_ + k0 + k8);
        __syncthreads();

#pragma unroll
        for (int kk = 0; kk < BK; kk += 16) {
            short8 afrag = *(const short8*)&shA[(wave * 32 + lm) * LDA + kk + kq];
#pragma unroll
            for (int j = 0; j < 4; ++j) {
                short8 bfrag = *(const short8*)&shB[(j * 32 + lm) * LDA + kk + kq];
                acc[j] = __builtin_amdgcn_mfma_f32_32x32x16_bf16(afrag, bfrag, acc[j], 0, 0, 0);
            }
        }
    }

    // C/D layout (HW-verified, m74/m101): col = lane&31, row = (reg&3) + 8*(reg>>2) + 4*(lane>>5)
    const float* bias = dir ? bias_b : bias_f;
#pragma unroll
    for (int j = 0; j < 4; ++j) {
        int col = n0 + j * 32 + lm;
        float bv = bias[col];
#pragma unroll
        for (int reg = 0; reg < 16; ++reg) {
            int row = m0 + wave * 32 + (reg & 3) + 8 * (reg >> 2) + 4 * (lane >> 5);
            xz[((size_t)dir * MROWS + row) * G_ + col] = __float2bfloat16(acc[j][reg] + bv);
        }
    }
}

// ---------------- recurrent scan (reg + LDS + small L2 stream) ----------------
__device__ inline float dot2f16(unsigned int rbits, unsigned int hbits, float acc) {
#if __has_builtin(__builtin_amdgcn_fdot2)
    return __builtin_amdgcn_fdot2(__builtin_bit_cast(v2h, rbits),
                                  __builtin_bit_cast(v2h, hbits), acc, false);
#else
    v2h r = __builtin_bit_cast(v2h, rbits);
    v2h h = __builtin_bit_cast(v2h, hbits);
    return acc + (float)r[0] * (float)h[0] + (float)r[1] * (float)h[1];
#endif
}

__device__ inline float sigmoidf(float x) { return 1.f / (1.f + __expf(-x)); }

// Pin a loaded uint4 into VGPRs so the allocator can't sink the load into the loop.
#define PIN4(v) asm volatile("" : "+v"(v.x), "+v"(v.y), "+v"(v.z), "+v"(v.w))

// One wg (512 threads = 8 waves = exactly 2 waves/EU at 1 wg/CU).
// amdgpu_waves_per_eu(2,2) caps occupancy at 2 waves/EU -> 256-VGPR budget, so the
// rec preload (192 VGPRs) actually stays register-resident (r3: launch_bounds 2nd arg
// caused 128-cap spills; r4: no bound -> heuristic chose 128 and re-sank the loads).
// Thread t owns columns c0=t (gates i/f) and c1=t+512 (gates c/o).
// rec split: kk 0..23 in VGPRs (192), kk 24..26 in LDS (48KB), kk 27..31 from L2 (80KB/step).
#define KKREG 24
#define KKLDS 3
__global__ __launch_bounds__(512) __attribute__((amdgpu_waves_per_eu(2, 2)))
void scan_kernel(
        const __hip_bfloat16* __restrict__ xz,    // [2][MROWS][G]
        const uint4* __restrict__ recQ,           // [2][32][1024] uint4
        const float* __restrict__ Wd,             // [S*H][2]
        const float* __restrict__ bd,             // [2]
        float* __restrict__ out) {                // [B][2], pre-zeroed
    int b = blockIdx.x, dir = blockIdx.y, tid = threadIdx.x;
    __shared__ __align__(16) uint4 sh_rec[KKLDS * G_];   // 48 KB
    __shared__ __align__(16) _Float16 sh_h[2][H_];       // 1 KB, double-buffered h
    __shared__ float sh_z[G_];                           // 4 KB z exchange
    __shared__ float rbuf[8];

    const uint4* rqbase = recQ + (size_t)dir * 32768;

    // preload rec kk=0..23 for both columns into registers, pinned
    uint4 rr0[KKREG], rr1[KKREG];
#pragma unroll
    for (int kk = 0; kk < KKREG; ++kk) {
        rr0[kk] = rqbase[kk * 1024 + tid];
        rr1[kk] = rqbase[kk * 1024 + tid + 512];
        PIN4(rr0[kk]);
        PIN4(rr1[kk]);
    }
    // stage rec kk=24..26 into LDS (contiguous copy)
#pragma unroll
    for (int j = 0; j < KKLDS * 2; ++j)
        sh_rec[j * 512 + tid] = rqbase[KKREG * 1024 + j * 512 + tid];
    const uint4* sp = rqbase + (KKREG + KKLDS) * 1024 + tid;   // stream part

    if (tid < H_) { sh_h[0][tid] = (_Float16)0.f; }
    float c = 0.f, pl0 = 0.f, pl1 = 0.f;
    const __hip_bfloat16* xzb = xz + ((size_t)dir * MROWS + (size_t)b * S_) * G_ + tid;
    __syncthreads();

    int p = 0;
    for (int s = 0; s < S_; ++s) {
        float xz0 = __bfloat162float(xzb[(size_t)s * G_]);
        float xz1 = __bfloat162float(xzb[(size_t)s * G_ + 512]);

        const uint4* hp = (const uint4*)&sh_h[p][0];          // 32 uint4 = 256 halves
        // two accumulators per column to break the dot2 dependency chain (4-cyc dep lat)
        float z0a = 0.f, z0b = 0.f, z1a = 0.f, z1b = 0.f;

        // register part
#pragma unroll
        for (int kk = 0; kk < KKREG; ++kk) {
            uint4 hv = hp[kk];                                 // wave-uniform broadcast
            uint4 r0 = rr0[kk];
            uint4 r1 = rr1[kk];
            z0a = dot2f16(r0.x, hv.x, z0a); z0b = dot2f16(r0.y, hv.y, z0b);
            z0a = dot2f16(r0.z, hv.z, z0a); z0b = dot2f16(r0.w, hv.w, z0b);
            z1a = dot2f16(r1.x, hv.x, z1a); z1b = dot2f16(r1.y, hv.y, z1b);
            z1a = dot2f16(r1.z, hv.z, z1a); z1b = dot2f16(r1.w, hv.w, z1b);
        }
        // LDS part
#pragma unroll
        for (int j = 0; j < KKLDS; ++j) {
            uint4 hv = hp[KKREG + j];
            uint4 r0 = sh_rec[j * 1024 + tid];
            uint4 r1 = sh_rec[j * 1024 + tid + 512];
            z0a = dot2f16(r0.x, hv.x, z0a); z0b = dot2f16(r0.y, hv.y, z0b);
            z0a = dot2f16(r0.z, hv.z, z0a); z0b = dot2f16(r0.w, hv.w, z0b);
            z1a = dot2f16(r1.x, hv.x, z1a); z1b = dot2f16(r1.y, hv.y, z1b);
            z1a = dot2f16(r1.z, hv.z, z1a); z1b = dot2f16(r1.w, hv.w, z1b);
        }
        // stream part from L2 (80 KB/step)
#pragma unroll
        for (int u = 0; u < 32 - KKREG - KKLDS; ++u) {
            uint4 r0 = sp[u * 1024];
            uint4 r1 = sp[u * 1024 + 512];
            uint4 hv = hp[KKREG + KKLDS + u];
            z0a = dot2f16(r0.x, hv.x, z0a); z0b = dot2f16(r0.y, hv.y, z0b);
            z0a = dot2f16(r0.z, hv.z, z0a); z0b = dot2f16(r0.w, hv.w, z0b);
            z1a = dot2f16(r1.x, hv.x, z1a); z1b = dot2f16(r1.y, hv.y, z1b);
            z1a = dot2f16(r1.z, hv.z, z1a); z1b = dot2f16(r1.w, hv.w, z1b);
        }
        sh_z[tid]       = z0a + z0b + xz0;
        sh_z[tid + 512] = z1a + z1b + xz1;
        __syncthreads();                                       // z visible; h-reads done

        if (tid < H_) {
            float zi = sh_z[tid];
            float zf = sh_z[H_ + tid];
            float zc = sh_z[2 * H_ + tid];
            float zo = sh_z[3 * H_ + tid];
            float ig = sigmoidf(zi);
            float fg = sigmoidf(zf);
            float og = sigmoidf(zo);
            float cc = fmaxf(zc, 0.f);
            c = fg * c + ig * cc;
            float h = og * fmaxf(c, 0.f);
            sh_h[p ^ 1][tid] = (_Float16)h;                    // write NEXT buffer

            int t = dir ? (S_ - 1 - s) : s;
            float2 w = ((const float2*)Wd)[t * H_ + tid];
            pl0 = fmaf(h, w.x, pl0);
            pl1 = fmaf(h, w.y, pl1);
        }
        __syncthreads();                                       // new h visible
        p ^= 1;
    }

    // reduction over threads 0..255 (4 waves)
    if (tid < H_) {
#pragma unroll
        for (int off = 32; off > 0; off >>= 1) {
            pl0 += __shfl_down(pl0, off);
            pl1 += __shfl_down(pl1, off);
        }
    }
    if (tid < H_ && (tid & 63) == 0) {
        int w = tid >> 6;
        rbuf[w] = pl0; rbuf[4 + w] = pl1;
    }
    __syncthreads();
    if (tid == 0) {
        float t0 = rbuf[0] + rbuf[1] + rbuf[2] + rbuf[3];
        float t1 = rbuf[4] + rbuf[5] + rbuf[6] + rbuf[7];
        atomicAdd(&out[b * 2 + 0], t0);
        atomicAdd(&out[b * 2 + 1], t1);
    }
    if (dir == 0 && tid < 2) atomicAdd(&out[b * 2 + tid], bd[tid]);
}

// ---------------- launch ----------------
extern "C" void kernel_launch(void* const* d_in, const int* in_sizes, int n_in,
                              void* d_out, int out_size, void* d_ws, size_t ws_size,
                              hipStream_t stream) {
    const float* x        = (const float*)d_in[0];
    const float* kernel_f = (const float*)d_in[1];
    const float* rec_f    = (const float*)d_in[2];
    const float* bias_f   = (const float*)d_in[3];
    const float* kernel_b = (const float*)d_in[4];
    const float* rec_b    = (const float*)d_in[5];
    const float* bias_b   = (const float*)d_in[6];
    const float* Wd       = (const float*)d_in[7];
    const float* bd       = (const float*)d_in[8];
    float* out = (float*)d_out;

    // workspace layout
    char* w = (char*)d_ws;
    __hip_bfloat16* xz  = (__hip_bfloat16*)w;                       // 2*32768*1024*2 = 134217728
    __hip_bfloat16* xbf = (__hip_bfloat16*)(w + 134217728);         // 64*512*768*2   = 50331648
    __hip_bfloat16* kT  = (__hip_bfloat16*)(w + 184549376);         // 2*1024*768*2   = 3145728
    unsigned int*  recQ = (unsigned int*) (w + 187695104);          // 2*32*1024*16   = 1048576

    // prep
    int nx = B_ * S_ * E_;
    cast_x_kernel<<<nx / (256 * 4), 256, 0, stream>>>(x, xbf, nx);
    prep_kT_kernel<<<dim3((E_ * G_) / 256, 2), 256, 0, stream>>>(kernel_f, kernel_b, kT);
    prep_recQ_kernel<<<dim3(131072 / 256, 2), 256, 0, stream>>>(rec_f, rec_b, recQ);

    // xz GEMM: grid (N/128, M/128, dirs)
    gemm_xz_kernel<<<dim3(G_ / TN, MROWS / TM, 2), 256, 0, stream>>>(xbf, kT, bias_f, bias_b, xz);

    // zero logits, then scan accumulates
    hipMemsetAsync(d_out, 0, (size_t)out_size * sizeof(float), stream);
    scan_kernel<<<dim3(B_, 2), 512, 0, stream>>>(xz, (const uint4*)recQ, Wd, bd, out);
}

// Round 6
// 1190.892 us; speedup vs baseline: 3.8108x; 1.2596x over previous
//
#include <hip/hip_runtime.h>
#include <hip/hip_bf16.h>
#include <hip/hip_fp16.h>

// Problem: B=64, S=512, E=768, H=256 (4H=1024). Bidirectional relu-LSTM + dense(2).
#define B_ 64
#define S_ 512
#define E_ 768
#define H_ 256
#define G_ 1024  // 4H
#define MROWS 32768  // B*S per direction

typedef float f32x4 __attribute__((ext_vector_type(4)));
typedef float f32x16 __attribute__((ext_vector_type(16)));
typedef short short8 __attribute__((ext_vector_type(8)));
typedef _Float16 v2h __attribute__((ext_vector_type(2)));
typedef unsigned int u32x4 __attribute__((ext_vector_type(4)));

// ---------------- prep kernels ----------------

__global__ void cast_x_kernel(const float* __restrict__ x, __hip_bfloat16* __restrict__ xbf, int n) {
    int i = (blockIdx.x * 256 + threadIdx.x) * 4;
    if (i >= n) return;
    float4 v = *(const float4*)(x + i);
    xbf[i + 0] = __float2bfloat16(v.x);
    xbf[i + 1] = __float2bfloat16(v.y);
    xbf[i + 2] = __float2bfloat16(v.z);
    xbf[i + 3] = __float2bfloat16(v.w);
}

// kernel [E][G] fp32 -> kT [dir][G][E] bf16 (transposed for MFMA B-fragments)
__global__ void prep_kT_kernel(const float* __restrict__ kf, const float* __restrict__ kb,
                               __hip_bfloat16* __restrict__ kT) {
    int idx = blockIdx.x * 256 + threadIdx.x;   // over E_*G_
    int dir = blockIdx.y;
    const float* src = dir ? kb : kf;
    int k = idx >> 10;        // E index
    int n = idx & 1023;       // G index
    float v = src[idx];       // coalesced read (n fast)
    kT[(size_t)dir * G_ * E_ + (size_t)n * E_ + k] = __float2bfloat16(v);
}

// rec [256][1024] fp32 -> recQ [dir][32][1024] uint4: half2 pairs of k = 8kk..8kk+7, col g
__global__ void prep_recQ_kernel(const float* __restrict__ rf, const float* __restrict__ rb,
                                 unsigned int* __restrict__ recQ) {
    int idx = blockIdx.x * 256 + threadIdx.x;   // over 32*1024*4 = 131072
    int dir = blockIdx.y;
    const float* src = dir ? rb : rf;
    int g  = idx & 1023;
    int u  = (idx >> 10) & 3;
    int kk = idx >> 12;
    int k0 = 8 * kk + 2 * u;
    float a = src[(size_t)k0 * G_ + g];
    float b = src[(size_t)(k0 + 1) * G_ + g];
    v2h p;
    p[0] = (_Float16)a;
    p[1] = (_Float16)b;
    recQ[(size_t)dir * 131072 + (size_t)kk * 4096 + g * 4 + u] = __builtin_bit_cast(unsigned int, p);
}

// ---------------- xz GEMM: LDS-tiled 128x128, BK=32, mfma 32x32x16 (unchanged r5) --------
#define TM 128
#define TN 128
#define BK 32
#define LDA 40   // padded LDS row stride in elements

__global__ __launch_bounds__(256) void gemm_xz_kernel(
        const __hip_bfloat16* __restrict__ xbf,   // [B*S][E]
        const __hip_bfloat16* __restrict__ kT,    // [2][G][E]
        const float* __restrict__ bias_f, const float* __restrict__ bias_b,
        __hip_bfloat16* __restrict__ xz) {        // [2][MROWS][G]
    int dir  = blockIdx.z;
    int nblk = blockIdx.x;      // 0..7   (G/128)
    int mblk = blockIdx.y;      // 0..255 (MROWS/128)
    int tid  = threadIdx.x;
    int wave = tid >> 6, lane = tid & 63;

    __shared__ __hip_bfloat16 shA[TM * LDA];
    __shared__ __hip_bfloat16 shB[TN * LDA];

    int m0 = mblk * TM;
    int n0 = nblk * TN;

    int rowl0 = tid >> 2;             // 0..63
    int rowl1 = rowl0 + 64;           // 64..127
    int k8    = (tid & 3) * 8;
    int ar0 = m0 + rowl0, ar1 = m0 + rowl1;
    int sa0 = (ar0 & ~511) | (dir ? (511 - (ar0 & 511)) : (ar0 & 511));
    int sa1 = (ar1 & ~511) | (dir ? (511 - (ar1 & 511)) : (ar1 & 511));
    const __hip_bfloat16* kbase = kT + (size_t)dir * G_ * E_;

    f32x16 acc[4] = {};

    int lm = lane & 31;
    int kq = (lane >> 5) * 8;

    for (int k0 = 0; k0 < E_; k0 += BK) {
        __syncthreads();
        *(short8*)&shA[rowl0 * LDA + k8] = *(const short8*)(xbf + (size_t)sa0 * E_ + k0 + k8);
        *(short8*)&shA[rowl1 * LDA + k8] = *(const short8*)(xbf + (size_t)sa1 * E_ + k0 + k8);
        *(short8*)&shB[rowl0 * LDA + k8] = *(const short8*)(kbase + (size_t)(n0 + rowl0) * E_ + k0 + k8);
        *(short8*)&shB[rowl1 * LDA + k8] = *(const short8*)(kbase + (size_t)(n0 + rowl1) * E_ + k0 + k8);
        __syncthreads();

#pragma unroll
        for (int kk = 0; kk < BK; kk += 16) {
            short8 afrag = *(const short8*)&shA[(wave * 32 + lm) * LDA + kk + kq];
#pragma unroll
            for (int j = 0; j < 4; ++j) {
                short8 bfrag = *(const short8*)&shB[(j * 32 + lm) * LDA + kk + kq];
                acc[j] = __builtin_amdgcn_mfma_f32_32x32x16_bf16(afrag, bfrag, acc[j], 0, 0, 0);
            }
        }
    }

    const float* bias = dir ? bias_b : bias_f;
#pragma unroll
    for (int j = 0; j < 4; ++j) {
        int col = n0 + j * 32 + lm;
        float bv = bias[col];
#pragma unroll
        for (int reg = 0; reg < 16; ++reg) {
            int row = m0 + wave * 32 + (reg & 3) + 8 * (reg >> 2) + 4 * (lane >> 5);
            xz[((size_t)dir * MROWS + row) * G_ + col] = __float2bfloat16(acc[j][reg] + bv);
        }
    }
}

// ---------------- recurrent scan: rec fully resident (192 k in VGPR, 64 k in LDS) --------
__device__ inline float dot2f16(unsigned int rbits, unsigned int hbits, float acc) {
#if __has_builtin(__builtin_amdgcn_fdot2)
    return __builtin_amdgcn_fdot2(__builtin_bit_cast(v2h, rbits),
                                  __builtin_bit_cast(v2h, hbits), acc, false);
#else
    v2h r = __builtin_bit_cast(v2h, rbits);
    v2h h = __builtin_bit_cast(v2h, hbits);
    return acc + (float)r[0] * (float)h[0] + (float)r[1] * (float)h[1];
#endif
}

__device__ inline float sigmoidf(float x) { return 1.f / (1.f + __expf(-x)); }

// One wg (512 threads = 8 waves) per (batch, dir). Thread t owns cols c0=t (gates i/f),
// c1=t+512 (gates c/o).
//
// Occupancy theory (r3/r4/r5 post-mortems): the backend picks the VGPR budget from
// achievable occupancy. LDS here = ~133 KB -> only 1 wg/CU fits -> 8 waves = 2/SIMD ->
// 256-VGPR budget, no attribute fight needed.
// Residency theory: C++ loads get sunk back into the loop (r4/r5). The preload below is
// asm-volatile global_load_dwordx4 — an asm def cannot be rematerialized/sunk, so the
// 192 rec VGPRs stay live. Explicit s_waitcnt since the compiler doesn't track asm loads.
#define KKREG 24   // kk-groups (8 k each) in VGPRs: 24*2 cols = 48 uint4 = 192 VGPRs
#define KKLDS 8    // kk-groups in LDS: 8 * 16 KB = 128 KB
__global__ __launch_bounds__(512) void scan_kernel(
        const __hip_bfloat16* __restrict__ xz,    // [2][MROWS][G]
        const uint4* __restrict__ recQ,           // [2][32][1024] uint4
        const float* __restrict__ Wd,             // [S*H][2]
        const float* __restrict__ bd,             // [2]
        float* __restrict__ out) {                // [B][2], pre-zeroed
    int b = blockIdx.x, dir = blockIdx.y, tid = threadIdx.x;
    __shared__ __align__(16) uint4 sh_rec[KKLDS * G_];   // 131072 B
    __shared__ __align__(16) _Float16 sh_h[2][H_];       // 1 KB, double-buffered h
    __shared__ float sh_z[G_];                           // 4 KB z exchange
    __shared__ float rbuf[8];

    const uint4* rqbase = recQ + (size_t)dir * 32768;

    // ---- asm-origin preload of rec kk=0..23 for both columns (cannot be sunk) ----
    u32x4 rr0[KKREG], rr1[KKREG];
    {
        unsigned long long a0 = (unsigned long long)(const void*)(rqbase + tid);
        unsigned long long a1 = (unsigned long long)(const void*)(rqbase + tid + 512);
#pragma unroll
        for (int kk = 0; kk < KKREG; ++kk) {
            unsigned long long ka0 = a0 + (unsigned long long)kk * 16384ull;
            unsigned long long ka1 = a1 + (unsigned long long)kk * 16384ull;
            asm volatile("global_load_dwordx4 %0, %1, off" : "=v"(rr0[kk]) : "v"(ka0));
            asm volatile("global_load_dwordx4 %0, %1, off" : "=v"(rr1[kk]) : "v"(ka1));
        }
        asm volatile("s_waitcnt vmcnt(0)" ::: "memory");
    }

    // ---- stage rec kk=24..31 into LDS (contiguous, coalesced) ----
#pragma unroll
    for (int j = 0; j < KKLDS * 2; ++j)
        sh_rec[j * 512 + tid] = rqbase[KKREG * 1024 + j * 512 + tid];

    if (tid < H_) { sh_h[0][tid] = (_Float16)0.f; }
    float c = 0.f, pl0 = 0.f, pl1 = 0.f;
    const __hip_bfloat16* xzb = xz + ((size_t)dir * MROWS + (size_t)b * S_) * G_ + tid;
    __syncthreads();

    int p = 0;
    for (int s = 0; s < S_; ++s) {
        float xz0 = __bfloat162float(xzb[(size_t)s * G_]);
        float xz1 = __bfloat162float(xzb[(size_t)s * G_ + 512]);
        // hoist Wd load for this step (independent of z)
        float2 wv = {0.f, 0.f};
        int t = dir ? (S_ - 1 - s) : s;
        if (tid < H_) wv = ((const float2*)Wd)[t * H_ + tid];

        const uint4* hp = (const uint4*)&sh_h[p][0];          // 32 uint4 = 256 halves
        float z0a = 0.f, z0b = 0.f, z1a = 0.f, z1b = 0.f;

        // register part (kk 0..23)
#pragma unroll
        for (int kk = 0; kk < KKREG; ++kk) {
            uint4 hv = hp[kk];                                 // wave-uniform broadcast
            u32x4 r0 = rr0[kk];
            u32x4 r1 = rr1[kk];
            z0a = dot2f16(r0.x, hv.x, z0a); z0b = dot2f16(r0.y, hv.y, z0b);
            z0a = dot2f16(r0.z, hv.z, z0a); z0b = dot2f16(r0.w, hv.w, z0b);
            z1a = dot2f16(r1.x, hv.x, z1a); z1b = dot2f16(r1.y, hv.y, z1b);
            z1a = dot2f16(r1.z, hv.z, z1a); z1b = dot2f16(r1.w, hv.w, z1b);
        }
        // LDS part (kk 24..31): lanes read consecutive 16B chunks -> 2-way aliasing (free)
#pragma unroll
        for (int j = 0; j < KKLDS; ++j) {
            uint4 hv = hp[KKREG + j];
            uint4 r0 = sh_rec[j * 1024 + tid];
            uint4 r1 = sh_rec[j * 1024 + tid + 512];
            z0a = dot2f16(r0.x, hv.x, z0a); z0b = dot2f16(r0.y, hv.y, z0b);
            z0a = dot2f16(r0.z, hv.z, z0a); z0b = dot2f16(r0.w, hv.w, z0b);
            z1a = dot2f16(r1.x, hv.x, z1a); z1b = dot2f16(r1.y, hv.y, z1b);
            z1a = dot2f16(r1.z, hv.z, z1a); z1b = dot2f16(r1.w, hv.w, z1b);
        }
        sh_z[tid]       = z0a + z0b + xz0;
        sh_z[tid + 512] = z1a + z1b + xz1;
        __syncthreads();                                       // z visible; h-reads done

        if (tid < H_) {
            float zi = sh_z[tid];
            float zf = sh_z[H_ + tid];
            float zc = sh_z[2 * H_ + tid];
            float zo = sh_z[3 * H_ + tid];
            float ig = sigmoidf(zi);
            float fg = sigmoidf(zf);
            float og = sigmoidf(zo);
            float cc = fmaxf(zc, 0.f);
            c = fg * c + ig * cc;
            float h = og * fmaxf(c, 0.f);
            sh_h[p ^ 1][tid] = (_Float16)h;                    // write NEXT buffer

            pl0 = fmaf(h, wv.x, pl0);
            pl1 = fmaf(h, wv.y, pl1);
        }
        __syncthreads();                                       // new h visible
        p ^= 1;
    }

    // reduction over threads 0..255 (4 waves)
    if (tid < H_) {
#pragma unroll
        for (int off = 32; off > 0; off >>= 1) {
            pl0 += __shfl_down(pl0, off);
            pl1 += __shfl_down(pl1, off);
        }
    }
    if (tid < H_ && (tid & 63) == 0) {
        int w = tid >> 6;
        rbuf[w] = pl0; rbuf[4 + w] = pl1;
    }
    __syncthreads();
    if (tid == 0) {
        float t0 = rbuf[0] + rbuf[1] + rbuf[2] + rbuf[3];
        float t1 = rbuf[4] + rbuf[5] + rbuf[6] + rbuf[7];
        atomicAdd(&out[b * 2 + 0], t0);
        atomicAdd(&out[b * 2 + 1], t1);
    }
    if (dir == 0 && tid < 2) atomicAdd(&out[b * 2 + tid], bd[tid]);
}

// ---------------- launch ----------------
extern "C" void kernel_launch(void* const* d_in, const int* in_sizes, int n_in,
                              void* d_out, int out_size, void* d_ws, size_t ws_size,
                              hipStream_t stream) {
    const float* x        = (const float*)d_in[0];
    const float* kernel_f = (const float*)d_in[1];
    const float* rec_f    = (const float*)d_in[2];
    const float* bias_f   = (const float*)d_in[3];
    const float* kernel_b = (const float*)d_in[4];
    const float* rec_b    = (const float*)d_in[5];
    const float* bias_b   = (const float*)d_in[6];
    const float* Wd       = (const float*)d_in[7];
    const float* bd       = (const float*)d_in[8];
    float* out = (float*)d_out;

    // workspace layout
    char* w = (char*)d_ws;
    __hip_bfloat16* xz  = (__hip_bfloat16*)w;                       // 2*32768*1024*2 = 134217728
    __hip_bfloat16* xbf = (__hip_bfloat16*)(w + 134217728);         // 64*512*768*2   = 50331648
    __hip_bfloat16* kT  = (__hip_bfloat16*)(w + 184549376);         // 2*1024*768*2   = 3145728
    unsigned int*  recQ = (unsigned int*) (w + 187695104);          // 2*32*1024*16   = 1048576

    // prep
    int nx = B_ * S_ * E_;
    cast_x_kernel<<<nx / (256 * 4), 256, 0, stream>>>(x, xbf, nx);
    prep_kT_kernel<<<dim3((E_ * G_) / 256, 2), 256, 0, stream>>>(kernel_f, kernel_b, kT);
    prep_recQ_kernel<<<dim3(131072 / 256, 2), 256, 0, stream>>>(rec_f, rec_b, recQ);

    // xz GEMM: grid (N/128, M/128, dirs)
    gemm_xz_kernel<<<dim3(G_ / TN, MROWS / TM, 2), 256, 0, stream>>>(xbf, kT, bias_f, bias_b, xz);

    // zero logits, then scan accumulates
    hipMemsetAsync(d_out, 0, (size_t)out_size * sizeof(float), stream);
    scan_kernel<<<dim3(B_, 2), 512, 0, stream>>>(xz, (const uint4*)recQ, Wd, bd, out);
}